// Round 2
// baseline (315.752 us; speedup 1.0000x reference)
//
#include <hip/hip_runtime.h>
#include <math.h>

#define BATCH  2
#define SEQ    2048
#define DMODEL 1024
#define NH     16
#define HD     64
#define NQKV   3072
#define ROWS   (BATCH*SEQ)
#define QSCALE 0.18033688f   // 0.125 * log2(e): QK^T scores land in log2 domain

typedef unsigned short u16;
typedef unsigned int   u32;
typedef __bf16 bf16x8 __attribute__((ext_vector_type(8)));
typedef float  f32x4  __attribute__((ext_vector_type(4)));

typedef const __attribute__((address_space(1))) void* gptr_t;
typedef __attribute__((address_space(3))) void* lptr_t;

__device__ __forceinline__ void gload16(lptr_t l, const void* g) {
    __builtin_amdgcn_global_load_lds((gptr_t)g, l, 16, 0, 0);
}

__device__ __forceinline__ u16 f2bf(float f) {          // RNE f32->bf16
    unsigned int u = __float_as_uint(f);
    u += 0x7FFFu + ((u >> 16) & 1u);
    return (u16)(u >> 16);
}
__device__ __forceinline__ u32 pk2(float lo, float hi) { // pack 2 f32 -> 2 bf16
#if __has_builtin(__builtin_amdgcn_cvt_pk_bf16_f32)
    typedef __bf16 bf16x2 __attribute__((ext_vector_type(2)));
    union { bf16x2 v; u32 u; } cv;
    cv.v = __builtin_amdgcn_cvt_pk_bf16_f32(lo, hi);
    return cv.u;
#else
    return (u32)f2bf(lo) | ((u32)f2bf(hi) << 16);
#endif
}
__device__ __forceinline__ float fexp2(float x) {
#if __has_builtin(__builtin_amdgcn_exp2f)
    return __builtin_amdgcn_exp2f(x);
#else
    return exp2f(x);
#endif
}

// ---------------------------------------------------------------------------
// fused prep: f32->bf16 for x/qkv_w/out_w, rope cos/sin table, bias wtab.
// Blocks [0, NBC): convert; [NBC, NBC+256): rope table; [NBC+256, +128): wtab.
// ---------------------------------------------------------------------------
#define NBC ((ROWS*DMODEL + NQKV*DMODEL + DMODEL*DMODEL) / 1024)
__global__ void prep_kernel(const float* __restrict__ a,
                            const float* __restrict__ b,
                            const float* __restrict__ c,
                            u16* __restrict__ oa, u16* __restrict__ ob,
                            u16* __restrict__ oc,
                            const float* __restrict__ freqs, float* __restrict__ cs_tab,
                            const float* __restrict__ bias_p,
                            const float* __restrict__ bias_a,
                            float* __restrict__ wtab)
{
    const int na = ROWS*DMODEL, nb = NQKV*DMODEL;
    int blk = blockIdx.x;
    if (blk < NBC) {
        int i = (blk * 256 + threadIdx.x) * 4;
        const float* s; u16* d; int base;
        if (i < na)           { s = a; d = oa; base = i; }
        else if (i < na + nb) { s = b; d = ob; base = i - na; }
        else                  { s = c; d = oc; base = i - na - nb; }
        float4 v = *(const float4*)(s + base);
        u16 o[4] = { f2bf(v.x), f2bf(v.y), f2bf(v.z), f2bf(v.w) };
        *(uint2*)(d + base) = *(const uint2*)o;
    } else if (blk < NBC + 256) {
        int idx = (blk - NBC) * 256 + threadIdx.x;   // SEQ*32
        int s = idx >> 5, d = idx & 31;
        float sn, cs;
        sincosf((float)s * freqs[d], &sn, &cs);
        cs_tab[idx * 2]     = cs;
        cs_tab[idx * 2 + 1] = sn;
    } else {
        int idx = (blk - NBC - 256) * 256 + threadIdx.x;  // NH*SEQ
        int h = idx >> 11;
        int d = idx & (SEQ - 1);
        float p = fmaxf(bias_p[h], 0.01f);
        float aa = fmaxf(bias_a[h], 0.01f);
        wtab[idx] = __expf(-p * log1pf(aa * (float)d));
    }
}

// ---------------------------------------------------------------------------
// QKV GEMM with fused RoPE + layout epilogue (verified R6/R7). 128x128 tile.
// ---------------------------------------------------------------------------
__global__ __launch_bounds__(256) void gemm_qkv(
    const u16* __restrict__ A, const u16* __restrict__ B,
    const float* __restrict__ cs_tab,
    u16* __restrict__ Qb, u16* __restrict__ Kb, u16* __restrict__ Vt)
{
    const int K = DMODEL;
    __shared__ __align__(16) u16 As[128][32];
    __shared__ __align__(16) u16 Bs[128][32];
    const int tid  = threadIdx.x;
    const int wave = tid >> 6, lane = tid & 63;
    const int quad = lane >> 4, l16 = lane & 15;
    const int wrow = (wave >> 1) * 64, wcol = (wave & 1) * 64;
    const int bm = blockIdx.x * 128, bn = blockIdx.y * 128;

    const int srow = lane >> 2;                       // 0..15
    const int scol = ((lane & 3) ^ (srow & 3)) * 8;   // swizzled chunk (u16)
    const int fsw = (quad ^ (l16 & 3)) * 8;           // frag read swizzle

    f32x4 acc[4][4];
#pragma unroll
    for (int i = 0; i < 4; ++i)
#pragma unroll
        for (int j = 0; j < 4; ++j) acc[i][j] = (f32x4){0.f,0.f,0.f,0.f};

    const u16* Ag0 = A + (size_t)(bm + wave*32 + srow)      * K + scol;
    const u16* Ag1 = A + (size_t)(bm + wave*32 + 16 + srow) * K + scol;
    const u16* Bg0 = B + (size_t)(bn + wave*32 + srow)      * K + scol;
    const u16* Bg1 = B + (size_t)(bn + wave*32 + 16 + srow) * K + scol;

    for (int k0 = 0; k0 < K; k0 += 32) {
        __syncthreads();
        gload16((lptr_t)&As[wave*32][0],      Ag0 + k0);
        gload16((lptr_t)&As[wave*32 + 16][0], Ag1 + k0);
        gload16((lptr_t)&Bs[wave*32][0],      Bg0 + k0);
        gload16((lptr_t)&Bs[wave*32 + 16][0], Bg1 + k0);
        __syncthreads();
        bf16x8 af[4], bfr[4];
#pragma unroll
        for (int i = 0; i < 4; ++i)
            af[i] = *(const bf16x8*)&As[wrow + i*16 + l16][fsw];
#pragma unroll
        for (int j = 0; j < 4; ++j)
            bfr[j] = *(const bf16x8*)&Bs[wcol + j*16 + l16][fsw];
#pragma unroll
        for (int i = 0; i < 4; ++i)
#pragma unroll
            for (int j = 0; j < 4; ++j)
                acc[i][j] = __builtin_amdgcn_mfma_f32_16x16x32_bf16(af[i], bfr[j], acc[i][j], 0, 0, 0);
    }

    // ---- fused epilogue ----
    const int tcol = (bn + wcol) >> 6;          // global 64-col index, 0..47
    const int t = tcol >> 4, h = tcol & 15;     // tensor (q/k/v), head
    const int bq = bm >> 11;                    // batch (tile never crosses)
    const int sb = (bm & (SEQ - 1)) + wrow;     // s base of this quadrant
    const size_t hb = (size_t)(bq * NH + h) * SEQ * HD;

    if (t == 2) {
#pragma unroll
        for (int i = 0; i < 4; ++i) {
            const int s = sb + i*16 + quad*4;
#pragma unroll
            for (int j = 0; j < 4; ++j) {
                const int d = j*16 + l16;
                uint2 pv = make_uint2(pk2(acc[i][j][0], acc[i][j][1]),
                                      pk2(acc[i][j][2], acc[i][j][3]));
                *(uint2*)&Vt[hb + (size_t)d * SEQ + s] = pv;
            }
        }
    } else {
        const float sc = (t == 0) ? QSCALE : 1.0f;
        u16* dstb = ((t == 0) ? Qb : Kb) + hb;
#pragma unroll
        for (int i = 0; i < 4; ++i) {
#pragma unroll
            for (int r = 0; r < 4; ++r) {
                const int s = sb + i*16 + quad*4 + r;
                const float2* ct = (const float2*)(cs_tab + ((size_t)s * 32 + l16) * 2);
                float2 cs0 = ct[0];     // freq idx l16
                float2 cs1 = ct[16];    // freq idx l16+16
                float a0 = acc[i][0][r], a1 = acc[i][1][r];
                float a2 = acc[i][2][r], a3 = acc[i][3][r];
                u16* dst = dstb + (size_t)s * HD;
                dst[l16]      = f2bf((a0*cs0.x - a2*cs0.y) * sc);
                dst[16 + l16] = f2bf((a1*cs1.x - a3*cs1.y) * sc);
                dst[32 + l16] = f2bf((a0*cs0.y + a2*cs0.x) * sc);
                dst[48 + l16] = f2bf((a1*cs1.y + a3*cs1.x) * sc);
            }
        }
    }
}

// ---------------------------------------------------------------------------
// out-projection GEMM: 128x64 tile (M x N) -> 512 blocks = 2+/CU for overlap.
// Wave w: rows (w>>1)*64, cols (w&1)*32. LDS 12 KB.
// ---------------------------------------------------------------------------
__global__ __launch_bounds__(256) void gemm_out(
    const u16* __restrict__ A, const u16* __restrict__ B,
    float* __restrict__ Cout, int M, int N, int K)
{
    __shared__ __align__(16) u16 As[128][32];
    __shared__ __align__(16) u16 Bs[64][32];
    const int tid  = threadIdx.x;
    const int wave = tid >> 6, lane = tid & 63;
    const int quad = lane >> 4, l16 = lane & 15;
    const int wrow = (wave >> 1) * 64, wcol = (wave & 1) * 32;
    const int bm = blockIdx.x * 128, bn = blockIdx.y * 64;

    const int srow = lane >> 2;
    const int scol = ((lane & 3) ^ (srow & 3)) * 8;
    const int fsw = (quad ^ (l16 & 3)) * 8;

    f32x4 acc[4][2];
#pragma unroll
    for (int i = 0; i < 4; ++i)
#pragma unroll
        for (int j = 0; j < 2; ++j) acc[i][j] = (f32x4){0.f,0.f,0.f,0.f};

    const u16* Ag0 = A + (size_t)(bm + wave*32 + srow)      * K + scol;
    const u16* Ag1 = A + (size_t)(bm + wave*32 + 16 + srow) * K + scol;
    const u16* Bg0 = B + (size_t)(bn + wave*16 + srow)      * K + scol;

    for (int k0 = 0; k0 < K; k0 += 32) {
        __syncthreads();
        gload16((lptr_t)&As[wave*32][0],      Ag0 + k0);
        gload16((lptr_t)&As[wave*32 + 16][0], Ag1 + k0);
        gload16((lptr_t)&Bs[wave*16][0],      Bg0 + k0);
        __syncthreads();
        bf16x8 af[4], bfr[2];
#pragma unroll
        for (int i = 0; i < 4; ++i)
            af[i] = *(const bf16x8*)&As[wrow + i*16 + l16][fsw];
#pragma unroll
        for (int j = 0; j < 2; ++j)
            bfr[j] = *(const bf16x8*)&Bs[wcol + j*16 + l16][fsw];
#pragma unroll
        for (int i = 0; i < 4; ++i)
#pragma unroll
            for (int j = 0; j < 2; ++j)
                acc[i][j] = __builtin_amdgcn_mfma_f32_16x16x32_bf16(af[i], bfr[j], acc[i][j], 0, 0, 0);
    }

#pragma unroll
    for (int i = 0; i < 4; ++i)
#pragma unroll
        for (int j = 0; j < 2; ++j) {
            int col = bn + wcol + j*16 + l16;
#pragma unroll
            for (int r = 0; r < 4; ++r) {
                int row = bm + wrow + i*16 + quad*4 + r;
                Cout[(size_t)row * N + col] = acc[i][j][r];
            }
        }
}

// ---------------------------------------------------------------------------
// MFMA flash attention v7: v6 structure plus
//  (a) T14 async staging: K/V/w staged global->reg early (issued right after
//      the stage barrier, consumed at next tile top) so HBM latency hides
//      under QK+softmax+PV instead of draining vmcnt(0) at the barrier.
//      LDS layouts identical (per-lane source swizzle preserved); ds_write
//      dest is linear lane*16B exactly like the old global_load_lds DMA.
//  (b) phase-minimal P swizzle in the aliased K region: col ^ ((row>>1)&3)<<3
//      (8-u16 granular). v6's ((l16>>1)&1)*16 left each 16-lane phase on half
//      the banks -> 2x conflicts on P write and pf read.
// ---------------------------------------------------------------------------
__global__ __launch_bounds__(256, 4) void attn_mfma(
    const u16* __restrict__ Qb, const u16* __restrict__ Kb,
    const u16* __restrict__ Vt, const float* __restrict__ wtab,
    u16* __restrict__ attn_bf)
{
    // KPs: per-wave 32x64 u16 area. Phase 1: K rows [wave*32..+32) ([key][d],
    // 8-chunk rows, swizzled). Phase 2 (after kf preload): P column block
    // [q=0..63][key local 0..31], col XOR-swizzled by ((q>>1)&3)<<3.
    __shared__ __align__(16) u16 KPs[128*64];
    __shared__ __align__(16) u16 Vs[64*128];   // [d][key], 16-chunk rows, swizzled
    __shared__ u32 ws2[192];                   // packed {w[m], w[m+1]}
    __shared__ float lred[4][64];
    __shared__ float linv[64];

    const int tid = threadIdx.x;
    const int wave = tid >> 6, lane = tid & 63;
    const int quad = lane >> 4, l16 = lane & 15;
    const int q0 = blockIdx.x * 64, h = blockIdx.y, b = blockIdx.z;

    const u16* Qh = Qb + (size_t)(b * NH + h) * SEQ * HD;
    const u16* Kh = Kb + (size_t)(b * NH + h) * SEQ * HD;
    const u16* Vh = Vt + (size_t)(b * NH + h) * HD * SEQ;
    const float* wh = wtab + h * SEQ;

    // Q fragments (B-operand of S^T): all 64 q rows per wave, in registers
    bf16x8 qf0[4], qf1[4];
#pragma unroll
    for (int qj = 0; qj < 4; ++qj) {
        const u16* qr = Qh + (size_t)(q0 + qj*16 + l16) * HD + quad * 8;
        qf0[qj] = *(const bf16x8*)qr;
        qf1[qj] = *(const bf16x8*)(qr + 32);
    }

    // K staging source: 4 issues, 8 rows x 8 chunks each; chunk' = chunk ^ (row&7)
    const int ksrow = lane >> 3;                       // 0..7
    const int kscol = ((lane & 7) ^ ksrow) * 8;
    const u16* Kst[4];
#pragma unroll
    for (int i = 0; i < 4; ++i)
        Kst[i] = Kh + (size_t)(wave*32 + i*8 + ksrow) * HD + kscol;

    // V staging source: 4 issues, 4 rows x 16 chunks each; chunk' = chunk ^ (d&7)
    const int vsrow = lane >> 4;                       // 0..3
    const u16* Vst[4];
#pragma unroll
    for (int i = 0; i < 4; ++i) {
        int d = wave*16 + i*4 + vsrow;
        int vscol = ((lane & 15) ^ (d & 7)) * 8;
        Vst[i] = Vh + (size_t)d * SEQ + vscol;
    }

    const int sw   = (quad ^ (l16 & 7)) * 8;           // kf chunk offset
    const int psw  = ((l16 >> 1) & 3) << 3;            // P swizzle: row-keyed, 8-granular
    const int mb0  = 127 + l16 - wave*32 - quad*4 - 3; // w-window base (>=0)

    float l_p[4] = {0.f, 0.f, 0.f, 0.f};
    f32x4 o[4];
#pragma unroll
    for (int j = 0; j < 4; ++j) o[j] = (f32x4){0.f,0.f,0.f,0.f};

    // ---- T14 prologue: load tile 0 into regs ----
    uint4 kreg[4], vreg[4];
#pragma unroll
    for (int i = 0; i < 4; ++i) {
        kreg[i] = *(const uint4*)Kst[i];
        vreg[i] = *(const uint4*)Vst[i];
    }
    float wA = 0.f, wB = 0.f;
    if (tid < 192) {
        int i0 = (q0 - 0 - 127) + tid;
        int a0 = i0 < 0 ? -i0 : i0;  if (a0 > SEQ-1) a0 = SEQ-1;
        int i1 = i0 + 1;
        int a1 = i1 < 0 ? -i1 : i1;  if (a1 > SEQ-1) a1 = SEQ-1;
        wA = wh[a0]; wB = wh[a1];
    }

    for (int kt = 0; kt < SEQ / 128; ++kt) {
        __syncthreads();                   // prior tile's P/Vs/ws2 reads done
        // ---- write-late: regs -> LDS (same layouts as the old DMA) ----
#pragma unroll
        for (int i = 0; i < 4; ++i) {
            *(uint4*)&KPs[(wave*32 + i*8)*64  + lane*8] = kreg[i];
            *(uint4*)&Vs[(wave*16 + i*4)*128 + lane*8] = vreg[i];
        }
        if (tid < 192) ws2[tid] = pk2(wA, wB);
        __syncthreads();

        // ---- issue-early: next tile's K/V/w global loads ----
        if (kt + 1 < SEQ / 128) {
            const int k1 = (kt + 1) * 128;
#pragma unroll
            for (int i = 0; i < 4; ++i) {
                kreg[i] = *(const uint4*)(Kst[i] + (size_t)k1 * HD);
                vreg[i] = *(const uint4*)(Vst[i] + k1);
            }
            if (tid < 192) {
                int i0 = (q0 - k1 - 127) + tid;
                int a0 = i0 < 0 ? -i0 : i0;  if (a0 > SEQ-1) a0 = SEQ-1;
                int i1 = i0 + 1;
                int a1 = i1 < 0 ? -i1 : i1;  if (a1 > SEQ-1) a1 = SEQ-1;
                wA = wh[a0]; wB = wh[a1];
            }
        }

        // ---- preload BOTH key groups' K fragments; K area then dead ----
        bf16x8 kf[2][2];
#pragma unroll
        for (int kg = 0; kg < 2; ++kg) {
            const int krow = (wave*32 + kg*16 + l16) * 64;
            kf[kg][0] = *(const bf16x8*)&KPs[krow + sw];
            kf[kg][1] = *(const bf16x8*)&KPs[krow + (sw ^ 32)];
        }

        // ---- S^T = K * Q^T for this wave's 2x16 keys; softmax; P write ----
        // P goes into this wave's own (now dead) K area: wave-private, so no
        // barrier needed between the kf reads above and these writes.
#pragma unroll
        for (int kg = 0; kg < 2; ++kg) {
#pragma unroll
            for (int qj = 0; qj < 4; ++qj) {
                f32x4 z = (f32x4){0.f,0.f,0.f,0.f};
                z = __builtin_amdgcn_mfma_f32_16x16x32_bf16(kf[kg][0], qf0[qj], z, 0, 0, 0);
                z = __builtin_amdgcn_mfma_f32_16x16x32_bf16(kf[kg][1], qf1[qj], z, 0, 0, 0);
                const int mbase = mb0 + qj*16 - kg*16;
                u32 pA = ws2[mbase], pB = ws2[mbase + 2];
                float w3 = __uint_as_float(pA << 16);
                float w2 = __uint_as_float(pA & 0xffff0000u);
                float w1 = __uint_as_float(pB << 16);
                float w0 = __uint_as_float(pB & 0xffff0000u);
                float e0 = fexp2(z[0]) * w0, e1 = fexp2(z[1]) * w1;
                float e2 = fexp2(z[2]) * w2, e3 = fexp2(z[3]) * w3;
                l_p[qj] += (e0 + e1) + (e2 + e3);
                *(uint2*)&KPs[wave*2048 + (qj*16 + l16)*32
                              + ((kg*16 + quad*4) ^ psw)] =
                    make_uint2(pk2(e0, e1), pk2(e2, e3));
            }
        }
        __syncthreads();                   // P visible to all waves

        // ---- PV: O[q=wave rows][d] += P * V over 128 keys ----
        bf16x8 pf[4];
#pragma unroll
        for (int m = 0; m < 4; ++m)
            pf[m] = *(const bf16x8*)&KPs[m*2048 + (wave*16 + l16)*32
                                         + ((quad*8) ^ psw)];
#pragma unroll
        for (int j = 0; j < 4; ++j) {
            const int vrow = (j*16 + l16) * 128;
            const int vsw = l16 & 7;
#pragma unroll
            for (int m = 0; m < 4; ++m) {
                bf16x8 vf = *(const bf16x8*)&Vs[vrow + (((m*4 + quad) ^ vsw) * 8)];
                o[j] = __builtin_amdgcn_mfma_f32_16x16x32_bf16(pf[m], vf, o[j], 0, 0, 0);
            }
        }
    }

    // ---- epilogue: reduce l (quads via shfl, waves via LDS), store ----
#pragma unroll
    for (int qj = 0; qj < 4; ++qj) {
        float l = l_p[qj];
        l += __shfl_xor(l, 16);
        l += __shfl_xor(l, 32);
        if (quad == 0) lred[wave][qj*16 + l16] = l;
    }
    __syncthreads();
    if (tid < 64)
        linv[tid] = 1.0f / (lred[0][tid] + lred[1][tid] + lred[2][tid] + lred[3][tid]);
    __syncthreads();
#pragma unroll
    for (int r = 0; r < 4; ++r) {
        const int q = wave*16 + quad*4 + r;
        float inv = linv[q];
        u16* dst = attn_bf + (size_t)(b * SEQ + q0 + q) * DMODEL + h * HD;
#pragma unroll
        for (int j = 0; j < 4; ++j)
            dst[j*16 + l16] = f2bf(o[j][r] * inv);
    }
}

// ---------------------------------------------------------------------------
extern "C" void kernel_launch(void* const* d_in, const int* in_sizes, int n_in,
                              void* d_out, int out_size, void* d_ws, size_t ws_size,
                              hipStream_t stream)
{
    (void)in_sizes; (void)n_in; (void)out_size; (void)ws_size;
    const float* x      = (const float*)d_in[0];
    const float* qkv_w  = (const float*)d_in[1];
    const float* out_w  = (const float*)d_in[2];
    const float* bias_p = (const float*)d_in[3];
    const float* bias_a = (const float*)d_in[4];
    const float* freqs  = (const float*)d_in[5];
    float* out = (float*)d_out;

    // ws layout (bytes):
    //   [0, 8M)       attn_bf [4096][1024] bf16
    //   [8M, 16M)     Qb      [2][16][2048][64] bf16
    //   [24M, 32M)    x_bf    [4096][1024] bf16
    //   [32M, 38M)    w1_bf   [3072][1024] bf16
    //   [38M, 40M)    w2_bf   [1024][1024] bf16
    //   [40M, 48M)    Kb      [2][16][2048][64] bf16
    //   [48M, 56M)    Vt      [2][16][64][2048] bf16
    //   [56M, +128K)  wtab    [16][2048] f32 (exp of bias)
    //   [+128K,+640K) cs_tab  [2048][32][2] f32
    char* ws = (char*)d_ws;
    u16*   attn_bf = (u16*)ws;
    u16*   Qb      = (u16*)(ws + 8388608);
    u16*   x_bf    = (u16*)(ws + 25165824);
    u16*   w1_bf   = (u16*)(ws + 33554432);
    u16*   w2_bf   = (u16*)(ws + 39845888);
    u16*   Kb      = (u16*)(ws + 41943040);
    u16*   Vt      = (u16*)(ws + 50331648);
    float* wtab    = (float*)(ws + 58720256);
    float* cs_tab  = (float*)(ws + 58720256 + 131072);

    prep_kernel<<<dim3(NBC + 256 + 128), 256, 0, stream>>>(
        x, qkv_w, out_w, x_bf, w1_bf, w2_bf, freqs, cs_tab, bias_p, bias_a, wtab);

    gemm_qkv<<<dim3(ROWS/128, NQKV/128), 256, 0, stream>>>(x_bf, w1_bf, cs_tab, Qb, Kb, Vt);
    attn_mfma<<<dim3(SEQ/64, NH, BATCH), 256, 0, stream>>>(Qb, Kb, Vt, wtab, attn_bf);
    gemm_out<<<dim3(ROWS/128, DMODEL/64), 256, 0, stream>>>(attn_bf, w2_bf, out, ROWS, DMODEL, DMODEL);
}

// Round 3
// 221.911 us; speedup vs baseline: 1.4229x; 1.4229x over previous
//
#include <hip/hip_runtime.h>
#include <math.h>

#define BATCH  2
#define SEQ    2048
#define DMODEL 1024
#define NH     16
#define HD     64
#define NQKV   3072
#define ROWS   (BATCH*SEQ)
#define QSCALE 0.18033688f   // 0.125 * log2(e): QK^T scores land in log2 domain

typedef unsigned short u16;
typedef unsigned int   u32;
typedef __bf16 bf16x8 __attribute__((ext_vector_type(8)));
typedef float  f32x4  __attribute__((ext_vector_type(4)));

typedef const __attribute__((address_space(1))) void* gptr_t;
typedef __attribute__((address_space(3))) void* lptr_t;

__device__ __forceinline__ void gload16(lptr_t l, const void* g) {
    __builtin_amdgcn_global_load_lds((gptr_t)g, l, 16, 0, 0);
}

__device__ __forceinline__ u16 f2bf(float f) {          // RNE f32->bf16
    unsigned int u = __float_as_uint(f);
    u += 0x7FFFu + ((u >> 16) & 1u);
    return (u16)(u >> 16);
}
__device__ __forceinline__ u32 pk2(float lo, float hi) { // pack 2 f32 -> 2 bf16
#if __has_builtin(__builtin_amdgcn_cvt_pk_bf16_f32)
    typedef __bf16 bf16x2 __attribute__((ext_vector_type(2)));
    union { bf16x2 v; u32 u; } cv;
    cv.v = __builtin_amdgcn_cvt_pk_bf16_f32(lo, hi);
    return cv.u;
#else
    return (u32)f2bf(lo) | ((u32)f2bf(hi) << 16);
#endif
}
__device__ __forceinline__ float fexp2(float x) {
#if __has_builtin(__builtin_amdgcn_exp2f)
    return __builtin_amdgcn_exp2f(x);
#else
    return exp2f(x);
#endif
}

// ---------------------------------------------------------------------------
// fused prep: f32->bf16 for x/qkv_w/out_w, rope cos/sin table, bias wtab.
// Blocks [0, NBC): convert; [NBC, NBC+256): rope table; [NBC+256, +128): wtab.
// ---------------------------------------------------------------------------
#define NBC ((ROWS*DMODEL + NQKV*DMODEL + DMODEL*DMODEL) / 1024)
__global__ void prep_kernel(const float* __restrict__ a,
                            const float* __restrict__ b,
                            const float* __restrict__ c,
                            u16* __restrict__ oa, u16* __restrict__ ob,
                            u16* __restrict__ oc,
                            const float* __restrict__ freqs, float* __restrict__ cs_tab,
                            const float* __restrict__ bias_p,
                            const float* __restrict__ bias_a,
                            float* __restrict__ wtab)
{
    const int na = ROWS*DMODEL, nb = NQKV*DMODEL;
    int blk = blockIdx.x;
    if (blk < NBC) {
        int i = (blk * 256 + threadIdx.x) * 4;
        const float* s; u16* d; int base;
        if (i < na)           { s = a; d = oa; base = i; }
        else if (i < na + nb) { s = b; d = ob; base = i - na; }
        else                  { s = c; d = oc; base = i - na - nb; }
        float4 v = *(const float4*)(s + base);
        u16 o[4] = { f2bf(v.x), f2bf(v.y), f2bf(v.z), f2bf(v.w) };
        *(uint2*)(d + base) = *(const uint2*)o;
    } else if (blk < NBC + 256) {
        int idx = (blk - NBC) * 256 + threadIdx.x;   // SEQ*32
        int s = idx >> 5, d = idx & 31;
        float sn, cs;
        sincosf((float)s * freqs[d], &sn, &cs);
        cs_tab[idx * 2]     = cs;
        cs_tab[idx * 2 + 1] = sn;
    } else {
        int idx = (blk - NBC - 256) * 256 + threadIdx.x;  // NH*SEQ
        int h = idx >> 11;
        int d = idx & (SEQ - 1);
        float p = fmaxf(bias_p[h], 0.01f);
        float aa = fmaxf(bias_a[h], 0.01f);
        wtab[idx] = __expf(-p * log1pf(aa * (float)d));
    }
}

// ---------------------------------------------------------------------------
// QKV GEMM with fused RoPE + layout epilogue (verified R6/R7). 128x128 tile.
// ---------------------------------------------------------------------------
__global__ __launch_bounds__(256) void gemm_qkv(
    const u16* __restrict__ A, const u16* __restrict__ B,
    const float* __restrict__ cs_tab,
    u16* __restrict__ Qb, u16* __restrict__ Kb, u16* __restrict__ Vt)
{
    const int K = DMODEL;
    __shared__ __align__(16) u16 As[128][32];
    __shared__ __align__(16) u16 Bs[128][32];
    const int tid  = threadIdx.x;
    const int wave = tid >> 6, lane = tid & 63;
    const int quad = lane >> 4, l16 = lane & 15;
    const int wrow = (wave >> 1) * 64, wcol = (wave & 1) * 64;
    const int bm = blockIdx.x * 128, bn = blockIdx.y * 128;

    const int srow = lane >> 2;                       // 0..15
    const int scol = ((lane & 3) ^ (srow & 3)) * 8;   // swizzled chunk (u16)
    const int fsw = (quad ^ (l16 & 3)) * 8;           // frag read swizzle

    f32x4 acc[4][4];
#pragma unroll
    for (int i = 0; i < 4; ++i)
#pragma unroll
        for (int j = 0; j < 4; ++j) acc[i][j] = (f32x4){0.f,0.f,0.f,0.f};

    const u16* Ag0 = A + (size_t)(bm + wave*32 + srow)      * K + scol;
    const u16* Ag1 = A + (size_t)(bm + wave*32 + 16 + srow) * K + scol;
    const u16* Bg0 = B + (size_t)(bn + wave*32 + srow)      * K + scol;
    const u16* Bg1 = B + (size_t)(bn + wave*32 + 16 + srow) * K + scol;

    for (int k0 = 0; k0 < K; k0 += 32) {
        __syncthreads();
        gload16((lptr_t)&As[wave*32][0],      Ag0 + k0);
        gload16((lptr_t)&As[wave*32 + 16][0], Ag1 + k0);
        gload16((lptr_t)&Bs[wave*32][0],      Bg0 + k0);
        gload16((lptr_t)&Bs[wave*32 + 16][0], Bg1 + k0);
        __syncthreads();
        bf16x8 af[4], bfr[4];
#pragma unroll
        for (int i = 0; i < 4; ++i)
            af[i] = *(const bf16x8*)&As[wrow + i*16 + l16][fsw];
#pragma unroll
        for (int j = 0; j < 4; ++j)
            bfr[j] = *(const bf16x8*)&Bs[wcol + j*16 + l16][fsw];
#pragma unroll
        for (int i = 0; i < 4; ++i)
#pragma unroll
            for (int j = 0; j < 4; ++j)
                acc[i][j] = __builtin_amdgcn_mfma_f32_16x16x32_bf16(af[i], bfr[j], acc[i][j], 0, 0, 0);
    }

    // ---- fused epilogue ----
    const int tcol = (bn + wcol) >> 6;          // global 64-col index, 0..47
    const int t = tcol >> 4, h = tcol & 15;     // tensor (q/k/v), head
    const int bq = bm >> 11;                    // batch (tile never crosses)
    const int sb = (bm & (SEQ - 1)) + wrow;     // s base of this quadrant
    const size_t hb = (size_t)(bq * NH + h) * SEQ * HD;

    if (t == 2) {
#pragma unroll
        for (int i = 0; i < 4; ++i) {
            const int s = sb + i*16 + quad*4;
#pragma unroll
            for (int j = 0; j < 4; ++j) {
                const int d = j*16 + l16;
                uint2 pv = make_uint2(pk2(acc[i][j][0], acc[i][j][1]),
                                      pk2(acc[i][j][2], acc[i][j][3]));
                *(uint2*)&Vt[hb + (size_t)d * SEQ + s] = pv;
            }
        }
    } else {
        const float sc = (t == 0) ? QSCALE : 1.0f;
        u16* dstb = ((t == 0) ? Qb : Kb) + hb;
#pragma unroll
        for (int i = 0; i < 4; ++i) {
#pragma unroll
            for (int r = 0; r < 4; ++r) {
                const int s = sb + i*16 + quad*4 + r;
                const float2* ct = (const float2*)(cs_tab + ((size_t)s * 32 + l16) * 2);
                float2 cs0 = ct[0];     // freq idx l16
                float2 cs1 = ct[16];    // freq idx l16+16
                float a0 = acc[i][0][r], a1 = acc[i][1][r];
                float a2 = acc[i][2][r], a3 = acc[i][3][r];
                u16* dst = dstb + (size_t)s * HD;
                dst[l16]      = f2bf((a0*cs0.x - a2*cs0.y) * sc);
                dst[16 + l16] = f2bf((a1*cs1.x - a3*cs1.y) * sc);
                dst[32 + l16] = f2bf((a0*cs0.y + a2*cs0.x) * sc);
                dst[48 + l16] = f2bf((a1*cs1.y + a3*cs1.x) * sc);
            }
        }
    }
}

// ---------------------------------------------------------------------------
// out-projection GEMM: 128x64 tile (M x N) -> 512 blocks = 2+/CU for overlap.
// Wave w: rows (w>>1)*64, cols (w&1)*32. LDS 12 KB.
// ---------------------------------------------------------------------------
__global__ __launch_bounds__(256) void gemm_out(
    const u16* __restrict__ A, const u16* __restrict__ B,
    float* __restrict__ Cout, int M, int N, int K)
{
    __shared__ __align__(16) u16 As[128][32];
    __shared__ __align__(16) u16 Bs[64][32];
    const int tid  = threadIdx.x;
    const int wave = tid >> 6, lane = tid & 63;
    const int quad = lane >> 4, l16 = lane & 15;
    const int wrow = (wave >> 1) * 64, wcol = (wave & 1) * 32;
    const int bm = blockIdx.x * 128, bn = blockIdx.y * 64;

    const int srow = lane >> 2;
    const int scol = ((lane & 3) ^ (srow & 3)) * 8;
    const int fsw = (quad ^ (l16 & 3)) * 8;

    f32x4 acc[4][2];
#pragma unroll
    for (int i = 0; i < 4; ++i)
#pragma unroll
        for (int j = 0; j < 2; ++j) acc[i][j] = (f32x4){0.f,0.f,0.f,0.f};

    const u16* Ag0 = A + (size_t)(bm + wave*32 + srow)      * K + scol;
    const u16* Ag1 = A + (size_t)(bm + wave*32 + 16 + srow) * K + scol;
    const u16* Bg0 = B + (size_t)(bn + wave*16 + srow)      * K + scol;

    for (int k0 = 0; k0 < K; k0 += 32) {
        __syncthreads();
        gload16((lptr_t)&As[wave*32][0],      Ag0 + k0);
        gload16((lptr_t)&As[wave*32 + 16][0], Ag1 + k0);
        gload16((lptr_t)&Bs[wave*16][0],      Bg0 + k0);
        __syncthreads();
        bf16x8 af[4], bfr[2];
#pragma unroll
        for (int i = 0; i < 4; ++i)
            af[i] = *(const bf16x8*)&As[wrow + i*16 + l16][fsw];
#pragma unroll
        for (int j = 0; j < 2; ++j)
            bfr[j] = *(const bf16x8*)&Bs[wcol + j*16 + l16][fsw];
#pragma unroll
        for (int i = 0; i < 4; ++i)
#pragma unroll
            for (int j = 0; j < 2; ++j)
                acc[i][j] = __builtin_amdgcn_mfma_f32_16x16x32_bf16(af[i], bfr[j], acc[i][j], 0, 0, 0);
    }

#pragma unroll
    for (int i = 0; i < 4; ++i)
#pragma unroll
        for (int j = 0; j < 2; ++j) {
            int col = bn + wcol + j*16 + l16;
#pragma unroll
            for (int r = 0; r < 4; ++r) {
                int row = bm + wrow + i*16 + quad*4 + r;
                Cout[(size_t)row * N + col] = acc[i][j][r];
            }
        }
}

// ---------------------------------------------------------------------------
// MFMA flash attention v8:
//  - K never touches LDS: wave w only ever consumed its own staged K rows,
//    and stage-swizzle XOR frag-swizzle cancels to kf = K[key][quad*8] /
//    +32 -> load fragments straight from global (L2-resident). Kills the
//    K DMA (16 b128 LDS writes/blk/tile) and kf LDS reads (16 b128).
//  - P gets its own dedicated 16 KB region (no K/P alias), same total LDS
//    34816 B -> 4 blocks/CU. P swizzle = phase-minimal ((q>>1)&3)<<3 (the
//    v7 fix that cut conflicts 11.5M -> 6.3M).
//  - QK z-MFMAs (register-only) run between V-DMA issue and the drain
//    barrier, hiding part of the DMA latency. z[2][4] is produced+consumed
//    within one iteration (no loop-carried reg arrays - the v7 spill trap).
// ---------------------------------------------------------------------------
__global__ __launch_bounds__(256, 4) void attn_mfma(
    const u16* __restrict__ Qb, const u16* __restrict__ Kb,
    const u16* __restrict__ Vt, const float* __restrict__ wtab,
    u16* __restrict__ attn_bf)
{
    __shared__ __align__(16) u16 Ps[4*64*32];  // [keygroup][q][key^psw]
    __shared__ __align__(16) u16 Vs[64*128];   // [d][key], 16-chunk rows, swizzled
    __shared__ u32 ws2[192];                   // packed {w[m], w[m+1]}
    __shared__ float lred[4][64];
    __shared__ float linv[64];

    const int tid = threadIdx.x;
    const int wave = tid >> 6, lane = tid & 63;
    const int quad = lane >> 4, l16 = lane & 15;
    const int q0 = blockIdx.x * 64, h = blockIdx.y, b = blockIdx.z;

    const u16* Qh = Qb + (size_t)(b * NH + h) * SEQ * HD;
    const u16* Kh = Kb + (size_t)(b * NH + h) * SEQ * HD;
    const u16* Vh = Vt + (size_t)(b * NH + h) * HD * SEQ;
    const float* wh = wtab + h * SEQ;

    // Q fragments (B-operand of S^T): all 64 q rows per wave, in registers
    bf16x8 qf0[4], qf1[4];
#pragma unroll
    for (int qj = 0; qj < 4; ++qj) {
        const u16* qr = Qh + (size_t)(q0 + qj*16 + l16) * HD + quad * 8;
        qf0[qj] = *(const bf16x8*)qr;
        qf1[qj] = *(const bf16x8*)(qr + 32);
    }

    // K fragment base: this wave's keys, direct fragment layout
    const u16* Kf0 = Kh + (size_t)(wave*32 + l16) * HD + quad * 8;

    // V staging source: 4 issues, 4 rows x 16 chunks each; chunk' = chunk ^ (d&7)
    const int vsrow = lane >> 4;                       // 0..3
    const u16* Vst[4];
#pragma unroll
    for (int i = 0; i < 4; ++i) {
        int d = wave*16 + i*4 + vsrow;
        int vscol = ((lane & 15) ^ (d & 7)) * 8;
        Vst[i] = Vh + (size_t)d * SEQ + vscol;
    }

    const int psw  = ((l16 >> 1) & 3) << 3;            // P swizzle: row-keyed, 8-granular
    const int mb0  = 127 + l16 - wave*32 - quad*4 - 3; // w-window base (>=0)

    float l_p[4] = {0.f, 0.f, 0.f, 0.f};
    f32x4 o[4];
#pragma unroll
    for (int j = 0; j < 4; ++j) o[j] = (f32x4){0.f,0.f,0.f,0.f};

    for (int kt = 0; kt < SEQ / 128; ++kt) {
        const int k0 = kt * 128;

        // ---- K fragments: global -> reg, no LDS round trip ----
        bf16x8 kf[2][2];
#pragma unroll
        for (int kg = 0; kg < 2; ++kg) {
            const u16* kp = Kf0 + (size_t)(k0 + kg*16) * HD;
            kf[kg][0] = *(const bf16x8*)kp;
            kf[kg][1] = *(const bf16x8*)(kp + 32);
        }

        __syncthreads();                   // b1: prior tile's P/Vs/ws2 reads done
#pragma unroll
        for (int i = 0; i < 4; ++i)
            gload16((lptr_t)&Vs[(wave*16 + i*4)*128], Vst[i] + k0);
        if (tid < 192) {                   // signed bias window, bf16 pairs
            int i0 = (q0 - k0 - 127) + tid;
            int a0 = i0 < 0 ? -i0 : i0;  if (a0 > SEQ-1) a0 = SEQ-1;
            int i1 = i0 + 1;
            int a1 = i1 < 0 ? -i1 : i1;  if (a1 > SEQ-1) a1 = SEQ-1;
            ws2[tid] = pk2(wh[a0], wh[a1]);
        }

        // ---- z = K*Q^T (register-only) overlaps the V DMA in flight ----
        f32x4 z[2][4];
#pragma unroll
        for (int kg = 0; kg < 2; ++kg)
#pragma unroll
            for (int qj = 0; qj < 4; ++qj) {
                f32x4 zz = (f32x4){0.f,0.f,0.f,0.f};
                zz = __builtin_amdgcn_mfma_f32_16x16x32_bf16(kf[kg][0], qf0[qj], zz, 0, 0, 0);
                zz = __builtin_amdgcn_mfma_f32_16x16x32_bf16(kf[kg][1], qf1[qj], zz, 0, 0, 0);
                z[kg][qj] = zz;
            }
        __syncthreads();                   // b2: Vs + ws2 ready

        // ---- softmax; P write (wave's own key-group block) ----
#pragma unroll
        for (int kg = 0; kg < 2; ++kg) {
#pragma unroll
            for (int qj = 0; qj < 4; ++qj) {
                const int mbase = mb0 + qj*16 - kg*16;
                u32 pA = ws2[mbase], pB = ws2[mbase + 2];
                float w3 = __uint_as_float(pA << 16);
                float w2 = __uint_as_float(pA & 0xffff0000u);
                float w1 = __uint_as_float(pB << 16);
                float w0 = __uint_as_float(pB & 0xffff0000u);
                float e0 = fexp2(z[kg][qj][0]) * w0, e1 = fexp2(z[kg][qj][1]) * w1;
                float e2 = fexp2(z[kg][qj][2]) * w2, e3 = fexp2(z[kg][qj][3]) * w3;
                l_p[qj] += (e0 + e1) + (e2 + e3);
                *(uint2*)&Ps[wave*2048 + (qj*16 + l16)*32
                             + ((kg*16 + quad*4) ^ psw)] =
                    make_uint2(pk2(e0, e1), pk2(e2, e3));
            }
        }
        __syncthreads();                   // b3: P visible to all waves

        // ---- PV: O[q=wave rows][d] += P * V over 128 keys ----
        bf16x8 pf[4];
#pragma unroll
        for (int m = 0; m < 4; ++m)
            pf[m] = *(const bf16x8*)&Ps[m*2048 + (wave*16 + l16)*32
                                        + ((quad*8) ^ psw)];
#pragma unroll
        for (int j = 0; j < 4; ++j) {
            const int vrow = (j*16 + l16) * 128;
            const int vsw = l16 & 7;
#pragma unroll
            for (int m = 0; m < 4; ++m) {
                bf16x8 vf = *(const bf16x8*)&Vs[vrow + (((m*4 + quad) ^ vsw) * 8)];
                o[j] = __builtin_amdgcn_mfma_f32_16x16x32_bf16(pf[m], vf, o[j], 0, 0, 0);
            }
        }
    }

    // ---- epilogue: reduce l (quads via shfl, waves via LDS), store ----
#pragma unroll
    for (int qj = 0; qj < 4; ++qj) {
        float l = l_p[qj];
        l += __shfl_xor(l, 16);
        l += __shfl_xor(l, 32);
        if (quad == 0) lred[wave][qj*16 + l16] = l;
    }
    __syncthreads();
    if (tid < 64)
        linv[tid] = 1.0f / (lred[0][tid] + lred[1][tid] + lred[2][tid] + lred[3][tid]);
    __syncthreads();
#pragma unroll
    for (int r = 0; r < 4; ++r) {
        const int q = wave*16 + quad*4 + r;
        float inv = linv[q];
        u16* dst = attn_bf + (size_t)(b * SEQ + q0 + q) * DMODEL + h * HD;
#pragma unroll
        for (int j = 0; j < 4; ++j)
            dst[j*16 + l16] = f2bf(o[j][r] * inv);
    }
}

// ---------------------------------------------------------------------------
extern "C" void kernel_launch(void* const* d_in, const int* in_sizes, int n_in,
                              void* d_out, int out_size, void* d_ws, size_t ws_size,
                              hipStream_t stream)
{
    (void)in_sizes; (void)n_in; (void)out_size; (void)ws_size;
    const float* x      = (const float*)d_in[0];
    const float* qkv_w  = (const float*)d_in[1];
    const float* out_w  = (const float*)d_in[2];
    const float* bias_p = (const float*)d_in[3];
    const float* bias_a = (const float*)d_in[4];
    const float* freqs  = (const float*)d_in[5];
    float* out = (float*)d_out;

    // ws layout (bytes):
    //   [0, 8M)       attn_bf [4096][1024] bf16
    //   [8M, 16M)     Qb      [2][16][2048][64] bf16
    //   [24M, 32M)    x_bf    [4096][1024] bf16
    //   [32M, 38M)    w1_bf   [3072][1024] bf16
    //   [38M, 40M)    w2_bf   [1024][1024] bf16
    //   [40M, 48M)    Kb      [2][16][2048][64] bf16
    //   [48M, 56M)    Vt      [2][16][64][2048] bf16
    //   [56M, +128K)  wtab    [16][2048] f32 (exp of bias)
    //   [+128K,+640K) cs_tab  [2048][32][2] f32
    char* ws = (char*)d_ws;
    u16*   attn_bf = (u16*)ws;
    u16*   Qb      = (u16*)(ws + 8388608);
    u16*   x_bf    = (u16*)(ws + 25165824);
    u16*   w1_bf   = (u16*)(ws + 33554432);
    u16*   w2_bf   = (u16*)(ws + 39845888);
    u16*   Kb      = (u16*)(ws + 41943040);
    u16*   Vt      = (u16*)(ws + 50331648);
    float* wtab    = (float*)(ws + 58720256);
    float* cs_tab  = (float*)(ws + 58720256 + 131072);

    prep_kernel<<<dim3(NBC + 256 + 128), 256, 0, stream>>>(
        x, qkv_w, out_w, x_bf, w1_bf, w2_bf, freqs, cs_tab, bias_p, bias_a, wtab);

    gemm_qkv<<<dim3(ROWS/128, NQKV/128), 256, 0, stream>>>(x_bf, w1_bf, cs_tab, Qb, Kb, Vt);
    attn_mfma<<<dim3(SEQ/64, NH, BATCH), 256, 0, stream>>>(Qb, Kb, Vt, wtab, attn_bf);
    gemm_out<<<dim3(ROWS/128, DMODEL/64), 256, 0, stream>>>(attn_bf, w2_bf, out, ROWS, DMODEL, DMODEL);
}